// Round 1
// baseline (1835.338 us; speedup 1.0000x reference)
//
#include <hip/hip_runtime.h>
#include <stdint.h>

#define NN 50000
#define EE 600000
#define DD 128
#define LL 3

typedef __attribute__((ext_vector_type(8))) short short8;
typedef __attribute__((ext_vector_type(4))) float f32x4;

static __device__ __forceinline__ short f2bf(float f) {
    uint32_t u = __builtin_bit_cast(uint32_t, f);
    u += 0x7FFFu + ((u >> 16) & 1u);
    return (short)(u >> 16);
}

// ---------------- edge scatter: agg[dst] += w * h[src] ----------------
__global__ __launch_bounds__(256) void scatter_kernel(
    const float* __restrict__ h, const int* __restrict__ src,
    const int* __restrict__ dst, const float* __restrict__ w,
    float* __restrict__ agg)
{
    int e = blockIdx.x * 4 + (threadIdx.x >> 6);
    int lane = threadIdx.x & 63;
    int s = src[e];
    int d = dst[e];
    float we = w[e];
    const float2* hp = reinterpret_cast<const float2*>(h + (size_t)s * DD);
    float2 v = hp[lane];
    float* ap = agg + (size_t)d * DD + lane * 2;
    atomicAdd(ap, we * v.x);
    atomicAdd(ap + 1, we * v.y);
}

// ---------------- fused GEMM (bf16 MFMA) + BN stats ----------------
// MODE 0: x = h + agg           -> y = x @ W, stats(y)
// MODE 1: x = relu(y*sc + sh)   -> z = x @ W, stats(z)
template <int MODE>
__global__ __launch_bounds__(256) void gemm_mfma(
    const float* __restrict__ in0,   // h (MODE0) / y (MODE1)
    const float* __restrict__ in1,   // agg (MODE0) / unused
    const float* __restrict__ W,     // [128][128] f32 row-major
    const float* __restrict__ prm,   // [256] scale|shift (MODE1)
    float* __restrict__ out,
    float* __restrict__ stats)       // [256] sum|sumsq
{
    __shared__ short Wt[DD][136];    // W^T in bf16, padded stride

    const int t = threadIdx.x;
    // stage W^T as bf16 into LDS
    #pragma unroll
    for (int i = 0; i < 64; ++i) {
        int idx = t + i * 256;       // 16384 total
        int k = idx >> 7, j = idx & 127;
        Wt[j][k] = f2bf(W[idx]);
    }
    __syncthreads();

    const int lane = t & 63;
    const int wave = t >> 6;
    const int rgrp = wave >> 1;      // which 64-row half
    const int chalf = wave & 1;      // which 64-col half
    const int l15 = lane & 15, lg = lane >> 4;

    // B fragments: 4 col-tiles x 4 k-steps, held in registers
    short8 Bf[4][4];
    #pragma unroll
    for (int jt = 0; jt < 4; ++jt) {
        int j = chalf * 64 + jt * 16 + l15;
        #pragma unroll
        for (int kk = 0; kk < 4; ++kk) {
            int kb = kk * 32 + lg * 8;
            Bf[jt][kk] = *reinterpret_cast<const short8*>(&Wt[j][kb]);
        }
    }

    float psum[4] = {0.f, 0.f, 0.f, 0.f};
    float psq[4]  = {0.f, 0.f, 0.f, 0.f};

    #pragma unroll 1
    for (int s = 0; s < 4; ++s) {
        int row0 = blockIdx.x * 128 + rgrp * 64 + s * 16;
        if (row0 >= NN) break;
        int row = row0 + l15;
        const float* xr0 = in0 + (size_t)row * DD;

        short8 Af[4];
        #pragma unroll
        for (int kk = 0; kk < 4; ++kk) {
            int kb = kk * 32 + lg * 8;
            float v[8];
            if (MODE == 0) {
                float4 a0 = reinterpret_cast<const float4*>(xr0 + kb)[0];
                float4 a1 = reinterpret_cast<const float4*>(xr0 + kb)[1];
                const float* gr = in1 + (size_t)row * DD + kb;
                float4 b0 = reinterpret_cast<const float4*>(gr)[0];
                float4 b1 = reinterpret_cast<const float4*>(gr)[1];
                v[0]=a0.x+b0.x; v[1]=a0.y+b0.y; v[2]=a0.z+b0.z; v[3]=a0.w+b0.w;
                v[4]=a1.x+b1.x; v[5]=a1.y+b1.y; v[6]=a1.z+b1.z; v[7]=a1.w+b1.w;
            } else {
                float4 a0 = reinterpret_cast<const float4*>(xr0 + kb)[0];
                float4 a1 = reinterpret_cast<const float4*>(xr0 + kb)[1];
                float4 s0 = reinterpret_cast<const float4*>(prm + kb)[0];
                float4 s1 = reinterpret_cast<const float4*>(prm + kb)[1];
                float4 h0 = reinterpret_cast<const float4*>(prm + DD + kb)[0];
                float4 h1 = reinterpret_cast<const float4*>(prm + DD + kb)[1];
                v[0]=fmaxf(fmaf(a0.x,s0.x,h0.x),0.f);
                v[1]=fmaxf(fmaf(a0.y,s0.y,h0.y),0.f);
                v[2]=fmaxf(fmaf(a0.z,s0.z,h0.z),0.f);
                v[3]=fmaxf(fmaf(a0.w,s0.w,h0.w),0.f);
                v[4]=fmaxf(fmaf(a1.x,s1.x,h1.x),0.f);
                v[5]=fmaxf(fmaf(a1.y,s1.y,h1.y),0.f);
                v[6]=fmaxf(fmaf(a1.z,s1.z,h1.z),0.f);
                v[7]=fmaxf(fmaf(a1.w,s1.w,h1.w),0.f);
            }
            short8 af;
            #pragma unroll
            for (int q = 0; q < 8; ++q) af[q] = f2bf(v[q]);
            Af[kk] = af;
        }

        f32x4 acc[4] = {};
        #pragma unroll
        for (int jt = 0; jt < 4; ++jt)
            #pragma unroll
            for (int kk = 0; kk < 4; ++kk)
                acc[jt] = __builtin_amdgcn_mfma_f32_16x16x32_bf16(
                    Af[kk], Bf[jt][kk], acc[jt], 0, 0, 0);

        #pragma unroll
        for (int jt = 0; jt < 4; ++jt) {
            int col = chalf * 64 + jt * 16 + l15;
            #pragma unroll
            for (int i = 0; i < 4; ++i) {
                int r = row0 + lg * 4 + i;
                float val = acc[jt][i];
                out[(size_t)r * DD + col] = val;
                psum[jt] += val;
                psq[jt] += val * val;
            }
        }
    }

    // reduce stats over the 4 lane-groups, one atomic per feature per wave
    #pragma unroll
    for (int jt = 0; jt < 4; ++jt) {
        float s1 = psum[jt], s2 = psq[jt];
        s1 += __shfl_xor(s1, 16); s2 += __shfl_xor(s2, 16);
        s1 += __shfl_xor(s1, 32); s2 += __shfl_xor(s2, 32);
        if (lg == 0) {
            int f = chalf * 64 + jt * 16 + l15;
            atomicAdd(&stats[f], s1);
            atomicAdd(&stats[DD + f], s2);
        }
    }
}

// ---------------- BN params: scale/shift from sums ----------------
__global__ void bn_params(const float* __restrict__ stats,
                          const float* __restrict__ g,
                          const float* __restrict__ b,
                          float* __restrict__ prm)
{
    int j = threadIdx.x;  // 128
    float m = stats[j] * (1.0f / NN);
    float var = stats[DD + j] * (1.0f / NN) - m * m;
    float s = g[j] * rsqrtf(var + 1e-5f);
    prm[j] = s;
    prm[DD + j] = fmaf(-m, s, b[j]);
}

// ---------------- stats of relu(bn2(z)) ----------------
__global__ __launch_bounds__(256) void stats_relu(
    const float* __restrict__ z, const float* __restrict__ prm,
    float* __restrict__ stats)
{
    __shared__ float ssum[DD], ssq[DD];
    int t = threadIdx.x;
    if (t < DD) { ssum[t] = 0.f; ssq[t] = 0.f; }
    __syncthreads();

    int f = (t * 4) & 127;
    float4 sc = *reinterpret_cast<const float4*>(prm + f);
    float4 sh = *reinterpret_cast<const float4*>(prm + DD + f);
    float p0=0,p1=0,p2=0,p3=0,q0=0,q1=0,q2=0,q3=0;
    size_t stride = (size_t)gridDim.x * 1024;
    for (size_t idx = (size_t)blockIdx.x * 1024 + t * 4; idx < (size_t)NN * DD; idx += stride) {
        float4 zv = *reinterpret_cast<const float4*>(z + idx);
        float u0 = fmaxf(fmaf(zv.x, sc.x, sh.x), 0.f);
        float u1 = fmaxf(fmaf(zv.y, sc.y, sh.y), 0.f);
        float u2 = fmaxf(fmaf(zv.z, sc.z, sh.z), 0.f);
        float u3 = fmaxf(fmaf(zv.w, sc.w, sh.w), 0.f);
        p0 += u0; q0 += u0 * u0;
        p1 += u1; q1 += u1 * u1;
        p2 += u2; q2 += u2 * u2;
        p3 += u3; q3 += u3 * u3;
    }
    atomicAdd(&ssum[f + 0], p0); atomicAdd(&ssq[f + 0], q0);
    atomicAdd(&ssum[f + 1], p1); atomicAdd(&ssq[f + 1], q1);
    atomicAdd(&ssum[f + 2], p2); atomicAdd(&ssq[f + 2], q2);
    atomicAdd(&ssum[f + 3], p3); atomicAdd(&ssq[f + 3], q3);
    __syncthreads();
    if (t < DD) {
        atomicAdd(&stats[t], ssum[t]);
        atomicAdd(&stats[DD + t], ssq[t]);
    }
}

// ---------------- final: h = bn3(relu(bn2(z))) [+relu] ----------------
__global__ __launch_bounds__(256) void final_apply(
    const float* __restrict__ z, const float* __restrict__ prm2,
    const float* __restrict__ prm3, float* __restrict__ out, int do_relu)
{
    int t = threadIdx.x;
    int f = (t * 4) & 127;
    float4 s2 = *reinterpret_cast<const float4*>(prm2 + f);
    float4 h2 = *reinterpret_cast<const float4*>(prm2 + DD + f);
    float4 s3 = *reinterpret_cast<const float4*>(prm3 + f);
    float4 h3 = *reinterpret_cast<const float4*>(prm3 + DD + f);
    size_t stride = (size_t)gridDim.x * 1024;
    for (size_t idx = (size_t)blockIdx.x * 1024 + t * 4; idx < (size_t)NN * DD; idx += stride) {
        float4 zv = *reinterpret_cast<const float4*>(z + idx);
        float4 o;
        float u;
        u = fmaxf(fmaf(zv.x, s2.x, h2.x), 0.f); o.x = fmaf(u, s3.x, h3.x);
        u = fmaxf(fmaf(zv.y, s2.y, h2.y), 0.f); o.y = fmaf(u, s3.y, h3.y);
        u = fmaxf(fmaf(zv.z, s2.z, h2.z), 0.f); o.z = fmaf(u, s3.z, h3.z);
        u = fmaxf(fmaf(zv.w, s2.w, h2.w), 0.f); o.w = fmaf(u, s3.w, h3.w);
        if (do_relu) {
            o.x = fmaxf(o.x, 0.f); o.y = fmaxf(o.y, 0.f);
            o.z = fmaxf(o.z, 0.f); o.w = fmaxf(o.w, 0.f);
        }
        *reinterpret_cast<float4*>(out + idx) = o;
    }
}

extern "C" void kernel_launch(void* const* d_in, const int* in_sizes, int n_in,
                              void* d_out, int out_size, void* d_ws, size_t ws_size,
                              hipStream_t stream)
{
    const float* h0   = (const float*)d_in[0];
    const int*  edges = (const int*)d_in[1];
    const float* w    = (const float*)d_in[2];
    const float* W0s  = (const float*)d_in[3];
    const float* W1s  = (const float*)d_in[4];
    const float* bn1g = (const float*)d_in[5];
    const float* bn1b = (const float*)d_in[6];
    const float* bn2g = (const float*)d_in[7];
    const float* bn2b = (const float*)d_in[8];
    const float* bn3g = (const float*)d_in[9];
    const float* bn3b = (const float*)d_in[10];
    float* out = (float*)d_out;
    float* ws  = (float*)d_ws;

    const size_t ND = (size_t)NN * DD;
    float* A    = ws;              // agg, then z
    float* B    = ws + ND;         // y
    float* hbuf = ws + 2 * ND;     // h between layers
    float* stats = ws + 3 * ND;    // 9 stages x 256
    float* prms  = stats + 9 * 256;

    const int* src = edges;
    const int* dst = edges + EE;

    hipMemsetAsync(stats, 0, 9 * 256 * sizeof(float), stream);

    for (int i = 0; i < LL; ++i) {
        const float* hin = (i == 0) ? h0 : hbuf;
        float* hout = (i == LL - 1) ? out : hbuf;
        float* st0 = stats + (i * 3 + 0) * 256;
        float* st1 = stats + (i * 3 + 1) * 256;
        float* st2 = stats + (i * 3 + 2) * 256;
        float* pr0 = prms + (i * 3 + 0) * 256;
        float* pr1 = prms + (i * 3 + 1) * 256;
        float* pr2 = prms + (i * 3 + 2) * 256;

        hipMemsetAsync(A, 0, ND * sizeof(float), stream);
        scatter_kernel<<<EE / 4, 256, 0, stream>>>(hin, src, dst, w, A);

        gemm_mfma<0><<<(NN + 127) / 128, 256, 0, stream>>>(
            hin, A, W0s + (size_t)i * DD * DD, nullptr, B, st0);
        bn_params<<<1, 128, 0, stream>>>(st0, bn1g + i * DD, bn1b + i * DD, pr0);

        gemm_mfma<1><<<(NN + 127) / 128, 256, 0, stream>>>(
            B, nullptr, W1s + (size_t)i * DD * DD, pr0, A, st1);
        bn_params<<<1, 128, 0, stream>>>(st1, bn2g + i * DD, bn2b + i * DD, pr1);

        stats_relu<<<1024, 256, 0, stream>>>(A, pr1, st2);
        bn_params<<<1, 128, 0, stream>>>(st2, bn3g + i * DD, bn3b + i * DD, pr2);

        final_apply<<<2048, 256, 0, stream>>>(A, pr1, pr2, hout, (i != LL - 1) ? 1 : 0);
    }
}

// Round 2
// 676.276 us; speedup vs baseline: 2.7139x; 2.7139x over previous
//
#include <hip/hip_runtime.h>
#include <stdint.h>

#define NN 50000
#define EE 600000
#define DD 128
#define LL 3

typedef __attribute__((ext_vector_type(8))) short short8;
typedef __attribute__((ext_vector_type(4))) float f32x4;

static __device__ __forceinline__ short f2bf(float f) {
    uint32_t u = __builtin_bit_cast(uint32_t, f);
    u += 0x7FFFu + ((u >> 16) & 1u);
    return (short)(u >> 16);
}

// ---------------- CSR build: histogram of dst ----------------
__global__ __launch_bounds__(256) void hist_kernel(
    const int* __restrict__ dst, int* __restrict__ deg)
{
    int e = blockIdx.x * 256 + threadIdx.x;
    if (e < EE) atomicAdd(&deg[dst[e]], 1);
}

// ---------------- CSR build: exclusive scan (1 block) ----------------
__global__ __launch_bounds__(1024) void scan_kernel(
    const int* __restrict__ deg, int* __restrict__ off, int* __restrict__ cursor)
{
    __shared__ int part[1024];
    const int t = threadIdx.x;
    const int CH = 49;                       // 1024*49 >= 50000
    int base = t * CH;
    int s = 0;
    for (int i = 0; i < CH; ++i) {
        int idx = base + i;
        if (idx < NN) s += deg[idx];
    }
    part[t] = s;
    __syncthreads();
    for (int d = 1; d < 1024; d <<= 1) {
        int v = (t >= d) ? part[t - d] : 0;
        __syncthreads();
        part[t] += v;
        __syncthreads();
    }
    int excl = part[t] - s;
    for (int i = 0; i < CH; ++i) {
        int idx = base + i;
        if (idx < NN) {
            off[idx] = excl;
            cursor[idx] = excl;
            excl += deg[idx];
        }
    }
    if (t == 1023) off[NN] = EE;
}

// ---------------- CSR build: bin-scatter edges ----------------
__global__ __launch_bounds__(256) void binsort_kernel(
    const int* __restrict__ src, const int* __restrict__ dst,
    const float* __restrict__ w, int* __restrict__ cursor,
    int2* __restrict__ em)
{
    int e = blockIdx.x * 256 + threadIdx.x;
    if (e >= EE) return;
    int d = dst[e];
    int p = atomicAdd(&cursor[d], 1);
    em[p] = make_int2(src[e], __float_as_int(w[e]));
}

// ---------------- gather: agg[v] = sum_j w_j * h[src_j] ----------------
__global__ __launch_bounds__(256) void gather_kernel(
    const float* __restrict__ h, const int* __restrict__ off,
    const int2* __restrict__ em, float* __restrict__ agg)
{
    int v = blockIdx.x * 4 + (threadIdx.x >> 6);
    if (v >= NN) return;
    int lane = threadIdx.x & 63;
    int beg = off[v], end = off[v + 1];
    const float* hb = h + lane * 2;
    float ax = 0.f, ay = 0.f;
    int j = beg;
    for (; j + 1 < end; j += 2) {
        int2 e0 = em[j], e1 = em[j + 1];
        float w0 = __int_as_float(e0.y), w1 = __int_as_float(e1.y);
        float2 v0 = *reinterpret_cast<const float2*>(hb + (size_t)e0.x * DD);
        float2 v1 = *reinterpret_cast<const float2*>(hb + (size_t)e1.x * DD);
        ax = fmaf(w0, v0.x, ax); ay = fmaf(w0, v0.y, ay);
        ax = fmaf(w1, v1.x, ax); ay = fmaf(w1, v1.y, ay);
    }
    if (j < end) {
        int2 e0 = em[j];
        float w0 = __int_as_float(e0.y);
        float2 v0 = *reinterpret_cast<const float2*>(hb + (size_t)e0.x * DD);
        ax = fmaf(w0, v0.x, ax); ay = fmaf(w0, v0.y, ay);
    }
    float2 o; o.x = ax; o.y = ay;
    *reinterpret_cast<float2*>(agg + (size_t)v * DD + lane * 2) = o;
}

// ---------------- fused GEMM (bf16 MFMA) + BN stats ----------------
// MODE 0: x = h + agg           -> y = x @ W, stats(y)
// MODE 1: x = relu(y*sc + sh)   -> z = x @ W, stats(z)
template <int MODE>
__global__ __launch_bounds__(256) void gemm_mfma(
    const float* __restrict__ in0,   // h (MODE0) / y (MODE1)
    const float* __restrict__ in1,   // agg (MODE0) / unused
    const float* __restrict__ W,     // [128][128] f32 row-major
    const float* __restrict__ prm,   // [256] scale|shift (MODE1)
    float* __restrict__ out,
    float* __restrict__ stats)       // [256] sum|sumsq
{
    __shared__ short Wt[DD][136];    // W^T in bf16, padded stride

    const int t = threadIdx.x;
    #pragma unroll
    for (int i = 0; i < 64; ++i) {
        int idx = t + i * 256;
        int k = idx >> 7, j = idx & 127;
        Wt[j][k] = f2bf(W[idx]);
    }
    __syncthreads();

    const int lane = t & 63;
    const int wave = t >> 6;
    const int rgrp = wave >> 1;
    const int chalf = wave & 1;
    const int l15 = lane & 15, lg = lane >> 4;

    short8 Bf[4][4];
    #pragma unroll
    for (int jt = 0; jt < 4; ++jt) {
        int j = chalf * 64 + jt * 16 + l15;
        #pragma unroll
        for (int kk = 0; kk < 4; ++kk) {
            int kb = kk * 32 + lg * 8;
            Bf[jt][kk] = *reinterpret_cast<const short8*>(&Wt[j][kb]);
        }
    }

    float psum[4] = {0.f, 0.f, 0.f, 0.f};
    float psq[4]  = {0.f, 0.f, 0.f, 0.f};

    #pragma unroll 1
    for (int s = 0; s < 4; ++s) {
        int row0 = blockIdx.x * 128 + rgrp * 64 + s * 16;
        if (row0 >= NN) break;
        int row = row0 + l15;
        const float* xr0 = in0 + (size_t)row * DD;

        short8 Af[4];
        #pragma unroll
        for (int kk = 0; kk < 4; ++kk) {
            int kb = kk * 32 + lg * 8;
            float v[8];
            if (MODE == 0) {
                float4 a0 = reinterpret_cast<const float4*>(xr0 + kb)[0];
                float4 a1 = reinterpret_cast<const float4*>(xr0 + kb)[1];
                const float* gr = in1 + (size_t)row * DD + kb;
                float4 b0 = reinterpret_cast<const float4*>(gr)[0];
                float4 b1 = reinterpret_cast<const float4*>(gr)[1];
                v[0]=a0.x+b0.x; v[1]=a0.y+b0.y; v[2]=a0.z+b0.z; v[3]=a0.w+b0.w;
                v[4]=a1.x+b1.x; v[5]=a1.y+b1.y; v[6]=a1.z+b1.z; v[7]=a1.w+b1.w;
            } else {
                float4 a0 = reinterpret_cast<const float4*>(xr0 + kb)[0];
                float4 a1 = reinterpret_cast<const float4*>(xr0 + kb)[1];
                float4 s0 = reinterpret_cast<const float4*>(prm + kb)[0];
                float4 s1 = reinterpret_cast<const float4*>(prm + kb)[1];
                float4 h0 = reinterpret_cast<const float4*>(prm + DD + kb)[0];
                float4 h1 = reinterpret_cast<const float4*>(prm + DD + kb)[1];
                v[0]=fmaxf(fmaf(a0.x,s0.x,h0.x),0.f);
                v[1]=fmaxf(fmaf(a0.y,s0.y,h0.y),0.f);
                v[2]=fmaxf(fmaf(a0.z,s0.z,h0.z),0.f);
                v[3]=fmaxf(fmaf(a0.w,s0.w,h0.w),0.f);
                v[4]=fmaxf(fmaf(a1.x,s1.x,h1.x),0.f);
                v[5]=fmaxf(fmaf(a1.y,s1.y,h1.y),0.f);
                v[6]=fmaxf(fmaf(a1.z,s1.z,h1.z),0.f);
                v[7]=fmaxf(fmaf(a1.w,s1.w,h1.w),0.f);
            }
            short8 af;
            #pragma unroll
            for (int q = 0; q < 8; ++q) af[q] = f2bf(v[q]);
            Af[kk] = af;
        }

        f32x4 acc[4] = {};
        #pragma unroll
        for (int jt = 0; jt < 4; ++jt)
            #pragma unroll
            for (int kk = 0; kk < 4; ++kk)
                acc[jt] = __builtin_amdgcn_mfma_f32_16x16x32_bf16(
                    Af[kk], Bf[jt][kk], acc[jt], 0, 0, 0);

        #pragma unroll
        for (int jt = 0; jt < 4; ++jt) {
            int col = chalf * 64 + jt * 16 + l15;
            #pragma unroll
            for (int i = 0; i < 4; ++i) {
                int r = row0 + lg * 4 + i;
                float val = acc[jt][i];
                out[(size_t)r * DD + col] = val;
                psum[jt] += val;
                psq[jt] += val * val;
            }
        }
    }

    #pragma unroll
    for (int jt = 0; jt < 4; ++jt) {
        float s1 = psum[jt], s2 = psq[jt];
        s1 += __shfl_xor(s1, 16); s2 += __shfl_xor(s2, 16);
        s1 += __shfl_xor(s1, 32); s2 += __shfl_xor(s2, 32);
        if (lg == 0) {
            int f = chalf * 64 + jt * 16 + l15;
            atomicAdd(&stats[f], s1);
            atomicAdd(&stats[DD + f], s2);
        }
    }
}

// ---------------- BN params: scale/shift from sums ----------------
__global__ void bn_params(const float* __restrict__ stats,
                          const float* __restrict__ g,
                          const float* __restrict__ b,
                          float* __restrict__ prm)
{
    int j = threadIdx.x;  // 128
    float m = stats[j] * (1.0f / NN);
    float var = stats[DD + j] * (1.0f / NN) - m * m;
    float s = g[j] * rsqrtf(var + 1e-5f);
    prm[j] = s;
    prm[DD + j] = fmaf(-m, s, b[j]);
}

// ---------------- stats of relu(bn2(z)) ----------------
__global__ __launch_bounds__(256) void stats_relu(
    const float* __restrict__ z, const float* __restrict__ prm,
    float* __restrict__ stats)
{
    __shared__ float ssum[DD], ssq[DD];
    int t = threadIdx.x;
    if (t < DD) { ssum[t] = 0.f; ssq[t] = 0.f; }
    __syncthreads();

    int f = (t * 4) & 127;
    float4 sc = *reinterpret_cast<const float4*>(prm + f);
    float4 sh = *reinterpret_cast<const float4*>(prm + DD + f);
    float p0=0,p1=0,p2=0,p3=0,q0=0,q1=0,q2=0,q3=0;
    size_t stride = (size_t)gridDim.x * 1024;
    for (size_t idx = (size_t)blockIdx.x * 1024 + t * 4; idx < (size_t)NN * DD; idx += stride) {
        float4 zv = *reinterpret_cast<const float4*>(z + idx);
        float u0 = fmaxf(fmaf(zv.x, sc.x, sh.x), 0.f);
        float u1 = fmaxf(fmaf(zv.y, sc.y, sh.y), 0.f);
        float u2 = fmaxf(fmaf(zv.z, sc.z, sh.z), 0.f);
        float u3 = fmaxf(fmaf(zv.w, sc.w, sh.w), 0.f);
        p0 += u0; q0 += u0 * u0;
        p1 += u1; q1 += u1 * u1;
        p2 += u2; q2 += u2 * u2;
        p3 += u3; q3 += u3 * u3;
    }
    atomicAdd(&ssum[f + 0], p0); atomicAdd(&ssq[f + 0], q0);
    atomicAdd(&ssum[f + 1], p1); atomicAdd(&ssq[f + 1], q1);
    atomicAdd(&ssum[f + 2], p2); atomicAdd(&ssq[f + 2], q2);
    atomicAdd(&ssum[f + 3], p3); atomicAdd(&ssq[f + 3], q3);
    __syncthreads();
    if (t < DD) {
        atomicAdd(&stats[t], ssum[t]);
        atomicAdd(&stats[DD + t], ssq[t]);
    }
}

// ---------------- final: h = bn3(relu(bn2(z))) [+relu] ----------------
__global__ __launch_bounds__(256) void final_apply(
    const float* __restrict__ z, const float* __restrict__ prm2,
    const float* __restrict__ prm3, float* __restrict__ out, int do_relu)
{
    int t = threadIdx.x;
    int f = (t * 4) & 127;
    float4 s2 = *reinterpret_cast<const float4*>(prm2 + f);
    float4 h2 = *reinterpret_cast<const float4*>(prm2 + DD + f);
    float4 s3 = *reinterpret_cast<const float4*>(prm3 + f);
    float4 h3 = *reinterpret_cast<const float4*>(prm3 + DD + f);
    size_t stride = (size_t)gridDim.x * 1024;
    for (size_t idx = (size_t)blockIdx.x * 1024 + t * 4; idx < (size_t)NN * DD; idx += stride) {
        float4 zv = *reinterpret_cast<const float4*>(z + idx);
        float4 o;
        float u;
        u = fmaxf(fmaf(zv.x, s2.x, h2.x), 0.f); o.x = fmaf(u, s3.x, h3.x);
        u = fmaxf(fmaf(zv.y, s2.y, h2.y), 0.f); o.y = fmaf(u, s3.y, h3.y);
        u = fmaxf(fmaf(zv.z, s2.z, h2.z), 0.f); o.z = fmaf(u, s3.z, h3.z);
        u = fmaxf(fmaf(zv.w, s2.w, h2.w), 0.f); o.w = fmaf(u, s3.w, h3.w);
        if (do_relu) {
            o.x = fmaxf(o.x, 0.f); o.y = fmaxf(o.y, 0.f);
            o.z = fmaxf(o.z, 0.f); o.w = fmaxf(o.w, 0.f);
        }
        *reinterpret_cast<float4*>(out + idx) = o;
    }
}

extern "C" void kernel_launch(void* const* d_in, const int* in_sizes, int n_in,
                              void* d_out, int out_size, void* d_ws, size_t ws_size,
                              hipStream_t stream)
{
    const float* h0   = (const float*)d_in[0];
    const int*  edges = (const int*)d_in[1];
    const float* w    = (const float*)d_in[2];
    const float* W0s  = (const float*)d_in[3];
    const float* W1s  = (const float*)d_in[4];
    const float* bn1g = (const float*)d_in[5];
    const float* bn1b = (const float*)d_in[6];
    const float* bn2g = (const float*)d_in[7];
    const float* bn2b = (const float*)d_in[8];
    const float* bn3g = (const float*)d_in[9];
    const float* bn3b = (const float*)d_in[10];
    float* out = (float*)d_out;
    float* ws  = (float*)d_ws;

    const size_t ND = (size_t)NN * DD;
    float* A    = ws;                 // agg, then z
    float* B    = ws + ND;            // y
    float* hbuf = ws + 2 * ND;        // h between layers
    float* stats = ws + 3 * ND;       // 9 stages x 256
    float* prms  = stats + 9 * 256;   // 9 stages x 256
    int*   deg    = (int*)(prms + 9 * 256);
    int*   off    = deg + NN;         // NN+1
    int*   cursor = off + NN + 1;
    int2*  em     = (int2*)(cursor + NN + 1);  // EE entries

    const int* src = edges;
    const int* dst = edges + EE;

    // ---- one-time CSR build ----
    hipMemsetAsync(deg, 0, NN * sizeof(int), stream);
    hipMemsetAsync(stats, 0, 9 * 256 * sizeof(float), stream);
    hist_kernel<<<(EE + 255) / 256, 256, 0, stream>>>(dst, deg);
    scan_kernel<<<1, 1024, 0, stream>>>(deg, off, cursor);
    binsort_kernel<<<(EE + 255) / 256, 256, 0, stream>>>(src, dst, w, cursor, em);

    for (int i = 0; i < LL; ++i) {
        const float* hin = (i == 0) ? h0 : hbuf;
        float* hout = (i == LL - 1) ? out : hbuf;
        float* st0 = stats + (i * 3 + 0) * 256;
        float* st1 = stats + (i * 3 + 1) * 256;
        float* st2 = stats + (i * 3 + 2) * 256;
        float* pr0 = prms + (i * 3 + 0) * 256;
        float* pr1 = prms + (i * 3 + 1) * 256;
        float* pr2 = prms + (i * 3 + 2) * 256;

        gather_kernel<<<(NN + 3) / 4, 256, 0, stream>>>(hin, off, em, A);

        gemm_mfma<0><<<(NN + 127) / 128, 256, 0, stream>>>(
            hin, A, W0s + (size_t)i * DD * DD, nullptr, B, st0);
        bn_params<<<1, 128, 0, stream>>>(st0, bn1g + i * DD, bn1b + i * DD, pr0);

        gemm_mfma<1><<<(NN + 127) / 128, 256, 0, stream>>>(
            B, nullptr, W1s + (size_t)i * DD * DD, pr0, A, st1);
        bn_params<<<1, 128, 0, stream>>>(st1, bn2g + i * DD, bn2b + i * DD, pr1);

        stats_relu<<<1024, 256, 0, stream>>>(A, pr1, st2);
        bn_params<<<1, 128, 0, stream>>>(st2, bn3g + i * DD, bn3b + i * DD, pr2);

        final_apply<<<2048, 256, 0, stream>>>(A, pr1, pr2, hout, (i != LL - 1) ? 1 : 0);
    }
}

// Round 3
// 541.857 us; speedup vs baseline: 3.3871x; 1.2481x over previous
//
#include <hip/hip_runtime.h>
#include <stdint.h>

#define NN 50000
#define EE 600000
#define DD 128
#define LL 3
#define NB 196   // ceil(NN/256)

typedef __attribute__((ext_vector_type(8))) short short8;
typedef __attribute__((ext_vector_type(4))) float f32x4;

static __device__ __forceinline__ short f2bf(float f) {
    uint32_t u = __builtin_bit_cast(uint32_t, f);
    u += 0x7FFFu + ((u >> 16) & 1u);
    return (short)(u >> 16);
}

// ---------------- CSR build: histogram of dst ----------------
__global__ __launch_bounds__(256) void hist_kernel(
    const int* __restrict__ dst, int* __restrict__ deg)
{
    int e = blockIdx.x * 256 + threadIdx.x;
    if (e < EE) atomicAdd(&deg[dst[e]], 1);
}

// ---------------- scan phase A: per-block sums ----------------
__global__ __launch_bounds__(256) void scan_a(
    const int* __restrict__ deg, int* __restrict__ partials)
{
    int i = blockIdx.x * 256 + threadIdx.x;
    int v = (i < NN) ? deg[i] : 0;
    #pragma unroll
    for (int d = 1; d < 64; d <<= 1) v += __shfl_xor(v, d);
    __shared__ int wsum[4];
    if ((threadIdx.x & 63) == 0) wsum[threadIdx.x >> 6] = v;
    __syncthreads();
    if (threadIdx.x == 0)
        partials[blockIdx.x] = wsum[0] + wsum[1] + wsum[2] + wsum[3];
}

// ---------------- scan phase B: scan the 196 partials ----------------
__global__ __launch_bounds__(256) void scan_b(
    const int* __restrict__ partials, int* __restrict__ blockbase)
{
    __shared__ int s[256];
    int t = threadIdx.x;
    int v = (t < NB) ? partials[t] : 0;
    s[t] = v;
    __syncthreads();
    for (int d = 1; d < 256; d <<= 1) {
        int u = (t >= d) ? s[t - d] : 0;
        __syncthreads();
        s[t] += u;
        __syncthreads();
    }
    if (t < NB) blockbase[t] = s[t] - v;   // exclusive
}

// ---------------- scan phase C: intra-block scan + base ----------------
__global__ __launch_bounds__(256) void scan_c(
    const int* __restrict__ deg, const int* __restrict__ blockbase,
    int* __restrict__ off, int* __restrict__ cursor)
{
    __shared__ int s[256];
    int t = threadIdx.x;
    int i = blockIdx.x * 256 + t;
    int v = (i < NN) ? deg[i] : 0;
    s[t] = v;
    __syncthreads();
    for (int d = 1; d < 256; d <<= 1) {
        int u = (t >= d) ? s[t - d] : 0;
        __syncthreads();
        s[t] += u;
        __syncthreads();
    }
    int excl = blockbase[blockIdx.x] + s[t] - v;
    if (i < NN) { off[i] = excl; cursor[i] = excl; }
    if (i == 0) off[NN] = EE;
}

// ---------------- CSR build: bin-scatter edges ----------------
__global__ __launch_bounds__(256) void binsort_kernel(
    const int* __restrict__ src, const int* __restrict__ dst,
    const float* __restrict__ w, int* __restrict__ cursor,
    int2* __restrict__ em)
{
    int e = blockIdx.x * 256 + threadIdx.x;
    if (e >= EE) return;
    int d = dst[e];
    int p = atomicAdd(&cursor[d], 1);
    em[p] = make_int2(src[e], __float_as_int(w[e]));
}

// ---------------- gather: agg[v] = sum_j w_j * h[src_j] ----------------
__global__ __launch_bounds__(256) void gather_kernel(
    const float* __restrict__ h, const int* __restrict__ off,
    const int2* __restrict__ em, float* __restrict__ agg)
{
    int v = blockIdx.x * 4 + (threadIdx.x >> 6);
    if (v >= NN) return;
    int lane = threadIdx.x & 63;
    int beg = off[v], end = off[v + 1];
    const float* hb = h + lane * 2;
    float ax = 0.f, ay = 0.f;
    int j = beg;
    for (; j + 1 < end; j += 2) {
        int2 e0 = em[j], e1 = em[j + 1];
        float w0 = __int_as_float(e0.y), w1 = __int_as_float(e1.y);
        float2 v0 = *reinterpret_cast<const float2*>(hb + (size_t)e0.x * DD);
        float2 v1 = *reinterpret_cast<const float2*>(hb + (size_t)e1.x * DD);
        ax = fmaf(w0, v0.x, ax); ay = fmaf(w0, v0.y, ay);
        ax = fmaf(w1, v1.x, ax); ay = fmaf(w1, v1.y, ay);
    }
    if (j < end) {
        int2 e0 = em[j];
        float w0 = __int_as_float(e0.y);
        float2 v0 = *reinterpret_cast<const float2*>(hb + (size_t)e0.x * DD);
        ax = fmaf(w0, v0.x, ax); ay = fmaf(w0, v0.y, ay);
    }
    float2 o; o.x = ax; o.y = ay;
    *reinterpret_cast<float2*>(agg + (size_t)v * DD + lane * 2) = o;
}

// ---------------- fused GEMM (bf16 MFMA) + BN stats ----------------
// MODE 0: x = h + agg                       -> y = x @ W, stats(y)
// MODE 1: x = relu(y*sc+sh), sc/sh from st  -> z = x @ W, stats(z)
template <int MODE>
__global__ __launch_bounds__(256) void gemm_mfma(
    const float* __restrict__ in0,   // h (MODE0) / y (MODE1)
    const float* __restrict__ in1,   // agg (MODE0) / unused
    const float* __restrict__ W,     // [128][128] f32 row-major
    const float* __restrict__ stin,  // [256] sum|sumsq of y (MODE1)
    const float* __restrict__ g,     // bn gamma (MODE1)
    const float* __restrict__ b,     // bn beta (MODE1)
    float* __restrict__ out,
    float* __restrict__ stats)       // [256] sum|sumsq out
{
    __shared__ short Wt[DD][136];    // W^T in bf16, padded stride
    __shared__ float sc[DD], sh[DD];

    const int t = threadIdx.x;
    if (MODE == 1 && t < DD) {
        float m = stin[t] * (1.0f / NN);
        float var = stin[DD + t] * (1.0f / NN) - m * m;
        float s = g[t] * rsqrtf(var + 1e-5f);
        sc[t] = s;
        sh[t] = fmaf(-m, s, b[t]);
    }
    #pragma unroll
    for (int i = 0; i < 64; ++i) {
        int idx = t + i * 256;
        int k = idx >> 7, j = idx & 127;
        Wt[j][k] = f2bf(W[idx]);
    }
    __syncthreads();

    const int lane = t & 63;
    const int wave = t >> 6;
    const int rgrp = wave >> 1;
    const int chalf = wave & 1;
    const int l15 = lane & 15, lg = lane >> 4;

    short8 Bf[4][4];
    #pragma unroll
    for (int jt = 0; jt < 4; ++jt) {
        int j = chalf * 64 + jt * 16 + l15;
        #pragma unroll
        for (int kk = 0; kk < 4; ++kk) {
            int kb = kk * 32 + lg * 8;
            Bf[jt][kk] = *reinterpret_cast<const short8*>(&Wt[j][kb]);
        }
    }

    float psum[4] = {0.f, 0.f, 0.f, 0.f};
    float psq[4]  = {0.f, 0.f, 0.f, 0.f};

    #pragma unroll 1
    for (int s = 0; s < 4; ++s) {
        int row0 = blockIdx.x * 128 + rgrp * 64 + s * 16;
        if (row0 >= NN) break;
        int row = row0 + l15;
        const float* xr0 = in0 + (size_t)row * DD;

        short8 Af[4];
        #pragma unroll
        for (int kk = 0; kk < 4; ++kk) {
            int kb = kk * 32 + lg * 8;
            float v[8];
            if (MODE == 0) {
                float4 a0 = reinterpret_cast<const float4*>(xr0 + kb)[0];
                float4 a1 = reinterpret_cast<const float4*>(xr0 + kb)[1];
                const float* gr = in1 + (size_t)row * DD + kb;
                float4 b0 = reinterpret_cast<const float4*>(gr)[0];
                float4 b1 = reinterpret_cast<const float4*>(gr)[1];
                v[0]=a0.x+b0.x; v[1]=a0.y+b0.y; v[2]=a0.z+b0.z; v[3]=a0.w+b0.w;
                v[4]=a1.x+b1.x; v[5]=a1.y+b1.y; v[6]=a1.z+b1.z; v[7]=a1.w+b1.w;
            } else {
                float4 a0 = reinterpret_cast<const float4*>(xr0 + kb)[0];
                float4 a1 = reinterpret_cast<const float4*>(xr0 + kb)[1];
                float4 s0 = *reinterpret_cast<const float4*>(&sc[kb]);
                float4 s1 = *reinterpret_cast<const float4*>(&sc[kb + 4]);
                float4 h0 = *reinterpret_cast<const float4*>(&sh[kb]);
                float4 h1 = *reinterpret_cast<const float4*>(&sh[kb + 4]);
                v[0]=fmaxf(fmaf(a0.x,s0.x,h0.x),0.f);
                v[1]=fmaxf(fmaf(a0.y,s0.y,h0.y),0.f);
                v[2]=fmaxf(fmaf(a0.z,s0.z,h0.z),0.f);
                v[3]=fmaxf(fmaf(a0.w,s0.w,h0.w),0.f);
                v[4]=fmaxf(fmaf(a1.x,s1.x,h1.x),0.f);
                v[5]=fmaxf(fmaf(a1.y,s1.y,h1.y),0.f);
                v[6]=fmaxf(fmaf(a1.z,s1.z,h1.z),0.f);
                v[7]=fmaxf(fmaf(a1.w,s1.w,h1.w),0.f);
            }
            short8 af;
            #pragma unroll
            for (int q = 0; q < 8; ++q) af[q] = f2bf(v[q]);
            Af[kk] = af;
        }

        f32x4 acc[4] = {};
        #pragma unroll
        for (int jt = 0; jt < 4; ++jt)
            #pragma unroll
            for (int kk = 0; kk < 4; ++kk)
                acc[jt] = __builtin_amdgcn_mfma_f32_16x16x32_bf16(
                    Af[kk], Bf[jt][kk], acc[jt], 0, 0, 0);

        #pragma unroll
        for (int jt = 0; jt < 4; ++jt) {
            int col = chalf * 64 + jt * 16 + l15;
            #pragma unroll
            for (int i = 0; i < 4; ++i) {
                int r = row0 + lg * 4 + i;
                float val = acc[jt][i];
                out[(size_t)r * DD + col] = val;
                psum[jt] += val;
                psq[jt] += val * val;
            }
        }
    }

    #pragma unroll
    for (int jt = 0; jt < 4; ++jt) {
        float s1 = psum[jt], s2 = psq[jt];
        s1 += __shfl_xor(s1, 16); s2 += __shfl_xor(s2, 16);
        s1 += __shfl_xor(s1, 32); s2 += __shfl_xor(s2, 32);
        if (lg == 0) {
            int f = chalf * 64 + jt * 16 + l15;
            atomicAdd(&stats[f], s1);
            atomicAdd(&stats[DD + f], s2);
        }
    }
}

// ---------------- stats of relu(bn2(z)), bn2 params inline ----------------
__global__ __launch_bounds__(256) void stats_relu(
    const float* __restrict__ z, const float* __restrict__ stin,
    const float* __restrict__ g, const float* __restrict__ b,
    float* __restrict__ stats)
{
    __shared__ float ssum[DD], ssq[DD], sc[DD], sh[DD];
    int t = threadIdx.x;
    if (t < DD) {
        ssum[t] = 0.f; ssq[t] = 0.f;
        float m = stin[t] * (1.0f / NN);
        float var = stin[DD + t] * (1.0f / NN) - m * m;
        float s = g[t] * rsqrtf(var + 1e-5f);
        sc[t] = s;
        sh[t] = fmaf(-m, s, b[t]);
    }
    __syncthreads();

    int f = (t * 4) & 127;
    float4 scv = *reinterpret_cast<const float4*>(&sc[f]);
    float4 shv = *reinterpret_cast<const float4*>(&sh[f]);
    float p0=0,p1=0,p2=0,p3=0,q0=0,q1=0,q2=0,q3=0;
    size_t stride = (size_t)gridDim.x * 1024;
    for (size_t idx = (size_t)blockIdx.x * 1024 + t * 4; idx < (size_t)NN * DD; idx += stride) {
        float4 zv = *reinterpret_cast<const float4*>(z + idx);
        float u0 = fmaxf(fmaf(zv.x, scv.x, shv.x), 0.f);
        float u1 = fmaxf(fmaf(zv.y, scv.y, shv.y), 0.f);
        float u2 = fmaxf(fmaf(zv.z, scv.z, shv.z), 0.f);
        float u3 = fmaxf(fmaf(zv.w, scv.w, shv.w), 0.f);
        p0 += u0; q0 += u0 * u0;
        p1 += u1; q1 += u1 * u1;
        p2 += u2; q2 += u2 * u2;
        p3 += u3; q3 += u3 * u3;
    }
    atomicAdd(&ssum[f + 0], p0); atomicAdd(&ssq[f + 0], q0);
    atomicAdd(&ssum[f + 1], p1); atomicAdd(&ssq[f + 1], q1);
    atomicAdd(&ssum[f + 2], p2); atomicAdd(&ssq[f + 2], q2);
    atomicAdd(&ssum[f + 3], p3); atomicAdd(&ssq[f + 3], q3);
    __syncthreads();
    if (t < DD) {
        atomicAdd(&stats[t], ssum[t]);
        atomicAdd(&stats[DD + t], ssq[t]);
    }
}

// ------- final: h = bn3(relu(bn2(z))) [+relu], params inline -------
__global__ __launch_bounds__(256) void final_apply(
    const float* __restrict__ z,
    const float* __restrict__ st2in, const float* __restrict__ g2,
    const float* __restrict__ b2,
    const float* __restrict__ st3in, const float* __restrict__ g3,
    const float* __restrict__ b3,
    float* __restrict__ out, int do_relu)
{
    __shared__ float sc2[DD], sh2[DD], sc3[DD], sh3[DD];
    int t = threadIdx.x;
    if (t < DD) {
        float m = st2in[t] * (1.0f / NN);
        float var = st2in[DD + t] * (1.0f / NN) - m * m;
        float s = g2[t] * rsqrtf(var + 1e-5f);
        sc2[t] = s;
        sh2[t] = fmaf(-m, s, b2[t]);
        m = st3in[t] * (1.0f / NN);
        var = st3in[DD + t] * (1.0f / NN) - m * m;
        s = g3[t] * rsqrtf(var + 1e-5f);
        sc3[t] = s;
        sh3[t] = fmaf(-m, s, b3[t]);
    }
    __syncthreads();

    int f = (t * 4) & 127;
    float4 s2 = *reinterpret_cast<const float4*>(&sc2[f]);
    float4 h2 = *reinterpret_cast<const float4*>(&sh2[f]);
    float4 s3 = *reinterpret_cast<const float4*>(&sc3[f]);
    float4 h3 = *reinterpret_cast<const float4*>(&sh3[f]);
    size_t stride = (size_t)gridDim.x * 1024;
    for (size_t idx = (size_t)blockIdx.x * 1024 + t * 4; idx < (size_t)NN * DD; idx += stride) {
        float4 zv = *reinterpret_cast<const float4*>(z + idx);
        float4 o;
        float u;
        u = fmaxf(fmaf(zv.x, s2.x, h2.x), 0.f); o.x = fmaf(u, s3.x, h3.x);
        u = fmaxf(fmaf(zv.y, s2.y, h2.y), 0.f); o.y = fmaf(u, s3.y, h3.y);
        u = fmaxf(fmaf(zv.z, s2.z, h2.z), 0.f); o.z = fmaf(u, s3.z, h3.z);
        u = fmaxf(fmaf(zv.w, s2.w, h2.w), 0.f); o.w = fmaf(u, s3.w, h3.w);
        if (do_relu) {
            o.x = fmaxf(o.x, 0.f); o.y = fmaxf(o.y, 0.f);
            o.z = fmaxf(o.z, 0.f); o.w = fmaxf(o.w, 0.f);
        }
        *reinterpret_cast<float4*>(out + idx) = o;
    }
}

extern "C" void kernel_launch(void* const* d_in, const int* in_sizes, int n_in,
                              void* d_out, int out_size, void* d_ws, size_t ws_size,
                              hipStream_t stream)
{
    const float* h0   = (const float*)d_in[0];
    const int*  edges = (const int*)d_in[1];
    const float* w    = (const float*)d_in[2];
    const float* W0s  = (const float*)d_in[3];
    const float* W1s  = (const float*)d_in[4];
    const float* bn1g = (const float*)d_in[5];
    const float* bn1b = (const float*)d_in[6];
    const float* bn2g = (const float*)d_in[7];
    const float* bn2b = (const float*)d_in[8];
    const float* bn3g = (const float*)d_in[9];
    const float* bn3b = (const float*)d_in[10];
    float* out = (float*)d_out;
    float* ws  = (float*)d_ws;

    const size_t ND = (size_t)NN * DD;
    float* A    = ws;                 // agg, then z
    float* B    = ws + ND;            // y
    float* hbuf = ws + 2 * ND;        // h between layers
    float* stats = ws + 3 * ND;       // 9 stages x 256
    int*   deg      = (int*)(stats + 9 * 256);
    int*   off      = deg + NN;       // NN+1
    int*   cursor   = off + NN + 1;
    int*   partials = cursor + NN + 1;
    int*   blockbase = partials + NB;
    int2*  em       = (int2*)(blockbase + NB);  // EE entries

    const int* src = edges;
    const int* dst = edges + EE;

    // ---- one-time CSR build (per call; all phases parallel) ----
    hipMemsetAsync(deg, 0, NN * sizeof(int), stream);
    hipMemsetAsync(stats, 0, 9 * 256 * sizeof(float), stream);
    hist_kernel<<<(EE + 255) / 256, 256, 0, stream>>>(dst, deg);
    scan_a<<<NB, 256, 0, stream>>>(deg, partials);
    scan_b<<<1, 256, 0, stream>>>(partials, blockbase);
    scan_c<<<NB, 256, 0, stream>>>(deg, blockbase, off, cursor);
    binsort_kernel<<<(EE + 255) / 256, 256, 0, stream>>>(src, dst, w, cursor, em);

    for (int i = 0; i < LL; ++i) {
        const float* hin = (i == 0) ? h0 : hbuf;
        float* hout = (i == LL - 1) ? out : hbuf;
        float* st0 = stats + (i * 3 + 0) * 256;
        float* st1 = stats + (i * 3 + 1) * 256;
        float* st2 = stats + (i * 3 + 2) * 256;

        gather_kernel<<<(NN + 3) / 4, 256, 0, stream>>>(hin, off, em, A);

        gemm_mfma<0><<<(NN + 127) / 128, 256, 0, stream>>>(
            hin, A, W0s + (size_t)i * DD * DD, nullptr, nullptr, nullptr, B, st0);

        gemm_mfma<1><<<(NN + 127) / 128, 256, 0, stream>>>(
            B, nullptr, W1s + (size_t)i * DD * DD, st0, bn1g + i * DD, bn1b + i * DD, A, st1);

        stats_relu<<<1024, 256, 0, stream>>>(A, st1, bn2g + i * DD, bn2b + i * DD, st2);

        final_apply<<<2048, 256, 0, stream>>>(
            A, st1, bn2g + i * DD, bn2b + i * DD,
            st2, bn3g + i * DD, bn3b + i * DD, hout, (i != LL - 1) ? 1 : 0);
    }
}